// Round 5
// baseline (632.544 us; speedup 1.0000x reference)
//
#include <hip/hip_runtime.h>
#include <math.h>

#define NN 20000
#define NE 320000
#define NF (NN*64)

typedef short sh8_t  __attribute__((ext_vector_type(8)));
typedef float fl4_t  __attribute__((ext_vector_type(4)));

__device__ __forceinline__ float silu_f(float x){ return x / (1.0f + expf(-x)); }

__device__ __forceinline__ short f2bf(float f){
  unsigned u = __builtin_bit_cast(unsigned, f);
  unsigned r = (u + 0x7fffu + ((u >> 16) & 1u)) >> 16;
  return (short)r;
}
__device__ __forceinline__ float bf2f(short s){
  unsigned u = ((unsigned)(unsigned short)s) << 16;
  return __builtin_bit_cast(float, u);
}
__device__ __forceinline__ float bfu2f(unsigned short s){
  unsigned u = ((unsigned)s) << 16;
  return __builtin_bit_cast(float, u);
}

// ---- CSR build ----------------------------------------------------------
__global__ __launch_bounds__(256) void k_hist(
    const int* __restrict__ receivers, int* __restrict__ counts)
{
  int i = blockIdx.x*256 + threadIdx.x;
  atomicAdd(&counts[receivers[i]], 1);
}

__global__ __launch_bounds__(256) void k_scan(
    const int* __restrict__ counts, int* __restrict__ row_start, int* __restrict__ off2)
{
  __shared__ int part[256];
  __shared__ int excl[257];
  int t = threadIdx.x;
  int lo = t*79, hi = lo+79 < NN ? lo+79 : NN;
  int s = 0;
  for(int i=lo; i<hi; ++i) s += counts[i];
  part[t] = s;
  __syncthreads();
  if(t == 0){
    int a = 0;
    for(int i=0; i<256; ++i){ excl[i] = a; a += part[i]; }
    excl[256] = a;
  }
  __syncthreads();
  int a = excl[t];
  for(int i=lo; i<hi; ++i){
    int c = counts[i];
    row_start[i] = a; off2[i] = a;
    a += c;
  }
  if(t == 255) row_start[NN] = excl[256];
}

__global__ __launch_bounds__(256) void k_scatter(
    const int* __restrict__ receivers, int* __restrict__ off2, int* __restrict__ csr)
{
  int e = blockIdx.x*256 + threadIdx.x;
  int pos = atomicAdd(&off2[receivers[e]], 1);
  csr[pos] = e;
}

// ---- Permute edge data into CSR order -----------------------------------
// rperm[pos][0..7] = radial row; vperm[pos] = (y0,y1,y2, bitcast(sender))
__global__ __launch_bounds__(256) void k_permute(
    const int* __restrict__ csr, const float* __restrict__ radial,
    const float* __restrict__ vectors, const int* __restrict__ senders,
    float* __restrict__ rperm, float4* __restrict__ vperm)
{
  int pos = blockIdx.x*256 + threadIdx.x;   // 0..NE-1 exact
  int e = csr[pos];
  float4 r0 = *(const float4*)(radial + (size_t)e*8);
  float4 r1 = *(const float4*)(radial + (size_t)e*8 + 4);
  *(float4*)(rperm + (size_t)pos*8)     = r0;
  *(float4*)(rperm + (size_t)pos*8 + 4) = r1;
  float vx = vectors[3*e], vy = vectors[3*e+1], vz = vectors[3*e+2];
  float rinv = 1.0f/sqrtf(vx*vx + vy*vy + vz*vz + 1e-12f);
  float4 v;
  v.x = vx*rinv; v.y = vy*rinv; v.z = vz*rinv;
  v.w = __int_as_float(senders[e]);
  vperm[pos] = v;
}

// ---- Fragment-ordered bf16 stream for mlp_w2 ----------------------------
__global__ __launch_bounds__(256) void k_prep_w2(
    const float* __restrict__ w2, short* __restrict__ w2f)
{
  int i = blockIdx.x*256 + threadIdx.x;     // 0..20479
  int jp   = i & 7;
  int lane = (i >> 3) & 63;
  int frag = i >> 9;                        // 0..39
  int k2 = frag / 20, p = frag % 20;
  int j = p >> 2, T = p & 3;
  int k = k2*32 + (lane >> 4)*8 + jp;
  int n = j*64 + T*16 + (lane & 15);
  w2f[i] = f2bf(w2[k*320 + n]);
}

// Transpose per-species residual weights (g-major -> f-major).
__global__ __launch_bounds__(256) void k_transpose_res(
    const float* __restrict__ Ws, const float* __restrict__ Wv,
    float* __restrict__ Wst, float* __restrict__ Wvt)
{
  int i = blockIdx.x*256 + threadIdx.x;   // 0..40959
  int spec = i >> 12;
  int g = (i >> 6) & 63;
  int f = i & 63;
  Wst[spec*4096 + f*64 + g] = Ws[i];
  Wvt[spec*4096 + f*64 + g] = Wv[i];
}

// ---- Node pre-pass: h = feats @ W_in / 8, packed bf16x4 ------------------
__global__ __launch_bounds__(256) void k_node_pre(
    const float* __restrict__ node_feats, const float* __restrict__ W_in_s,
    const float* __restrict__ W_in_v, ushort4* __restrict__ h4)
{
  __shared__ float sh[4][4][64];
  int wave = threadIdx.x >> 6, lane = threadIdx.x & 63;
  int n = blockIdx.x*4 + wave;
  int o = n*64 + lane;
  float4 nf = *(const float4*)(node_feats + (size_t)o*4);
  sh[wave][0][lane]=nf.x; sh[wave][1][lane]=nf.y; sh[wave][2][lane]=nf.z; sh[wave][3][lane]=nf.w;
  __syncthreads();
  float as=0.f, av0=0.f, av1=0.f, av2=0.f;
  #pragma unroll 8
  for(int f=0; f<64; ++f){
    float ws = W_in_s[f*64+lane], wv = W_in_v[f*64+lane];
    as  += sh[wave][0][f]*ws;
    av0 += sh[wave][1][f]*wv;
    av1 += sh[wave][2][f]*wv;
    av2 += sh[wave][3][f]*wv;
  }
  ushort4 hv;
  hv.x = (unsigned short)f2bf(as *0.125f);
  hv.y = (unsigned short)f2bf(av0*0.125f);
  hv.z = (unsigned short)f2bf(av1*0.125f);
  hv.w = (unsigned short)f2bf(av2*0.125f);
  h4[o] = hv;
}

// ---- Receiver-centric fused edge kernel: no atomics, low VGPR ------------
__global__ __launch_bounds__(256, 4) void k_edge_recv(
    const int* __restrict__ row_start,
    const float* __restrict__ rperm, const float4* __restrict__ vperm,
    const float* __restrict__ mlp_w1, const short* __restrict__ w2f,
    const ushort4* __restrict__ h4, ushort4* __restrict__ agg4)
{
  __shared__ float hid[4][16][65];   // stride 65: <=2-way bank conflicts (free)
  __shared__ float ey[4][16][3];
  __shared__ int   esn[4][16];
  __shared__ float rad[4][128];
  int wave = threadIdx.x >> 6, lane = threadIdx.x & 63;
  int n = blockIdx.x*4 + wave;
  int start = row_start[n], end = row_start[n+1];
  int l15 = lane & 15, q = lane >> 4;

  float w1r[8];
  #pragma unroll
  for(int r=0; r<8; ++r) w1r[r] = mlp_w1[r*64+lane];

  float accS[4]  = {0.f,0.f,0.f,0.f};
  float accV0[4] = {0.f,0.f,0.f,0.f};
  float accV1[4] = {0.f,0.f,0.f,0.f};
  float accV2[4] = {0.f,0.f,0.f,0.f};

  for(int base = start; base < end; base += 16){
    int cnt = end - base; if(cnt > 16) cnt = 16;
    // coalesced staging from permuted streams
    {
      int p0 = base + (lane >> 3);
      int p1 = p0 + 8;
      float v0 = (p0 < end) ? rperm[(size_t)base*8 + lane]      : 0.f;
      float v1 = (p1 < end) ? rperm[(size_t)base*8 + 64 + lane] : 0.f;
      rad[wave][lane]      = v0;
      rad[wave][64 + lane] = v1;
      if(lane < 16){
        int pp = base + lane;
        if(pp < end){
          float4 v = vperm[pp];
          ey[wave][lane][0] = v.x; ey[wave][lane][1] = v.y; ey[wave][lane][2] = v.z;
          esn[wave][lane] = __float_as_int(v.w);
        } else {
          ey[wave][lane][0]=0.f; ey[wave][lane][1]=0.f; ey[wave][lane][2]=0.f;
          esn[wave][lane] = 0;
        }
      }
    }
    // hidden = silu(rad @ w1); pad rows exactly zero
    #pragma unroll
    for(int t=0; t<16; ++t){
      float acc = 0.f;
      #pragma unroll
      for(int r=0; r<8; ++r) acc += rad[wave][t*8+r]*w1r[r];
      hid[wave][t][lane] = silu_f(acc);
    }
    // A fragments (hi/lo split), kept for both k2
    sh8_t ahi[2], alo[2];
    #pragma unroll
    for(int k2=0; k2<2; ++k2){
      #pragma unroll
      for(int i=0; i<8; ++i){
        float a = hid[wave][l15][k2*32 + q*8 + i];
        short h = f2bf(a);
        ahi[k2][i] = h;
        alo[k2][i] = f2bf(a - bf2f(h));
      }
    }
    // per-T: only C[5] live at a time (VGPR control)
    #pragma unroll
    for(int T=0; T<4; ++T){
      fl4_t C[5];
      #pragma unroll
      for(int j=0; j<5; ++j) C[j] = (fl4_t){0.f,0.f,0.f,0.f};
      #pragma unroll
      for(int k2=0; k2<2; ++k2){
        const short* bb = w2f + (size_t)(k2*20 + T)*512 + lane*8;
        #pragma unroll
        for(int j=0; j<5; ++j){
          sh8_t b = *(const sh8_t*)(bb + (size_t)j*2048);
          C[j] = __builtin_amdgcn_mfma_f32_16x16x32_bf16(ahi[k2], b, C[j], 0, 0, 0);
          C[j] = __builtin_amdgcn_mfma_f32_16x16x32_bf16(alo[k2], b, C[j], 0, 0, 0);
        }
      }
      #pragma unroll
      for(int reg=0; reg<4; ++reg){
        int r = q*4 + reg;
        if(r < cnt){
          float y0 = ey[wave][r][0], y1 = ey[wave][r][1], y2 = ey[wave][r][2];
          int snd = esn[wave][r];
          ushort4 hh = h4[(size_t)snd*64 + T*16 + l15];
          float ss  = bfu2f(hh.x);
          float sv0 = bfu2f(hh.y), sv1 = bfu2f(hh.z), sv2 = bfu2f(hh.w);
          float dot = sv0*y0 + sv1*y1 + sv2*y2;
          float w0 = C[0][reg], w1v = C[1][reg], w2v = C[2][reg];
          float w3v = C[3][reg], w4v = C[4][reg];
          float w2s = w2v*ss;
          accS[T]  += w0*ss + w1v*dot;
          accV0[T] += w2s*y0 + w3v*sv0 + w4v*(sv1*y2 - sv2*y1);
          accV1[T] += w2s*y1 + w3v*sv1 + w4v*(sv2*y0 - sv0*y2);
          accV2[T] += w2s*y2 + w3v*sv2 + w4v*(sv0*y1 - sv1*y0);
        }
      }
    }
  }
  // reduce over 4 q-groups (rows) per column
  #pragma unroll
  for(int T=0; T<4; ++T){
    accS[T]  += __shfl_xor(accS[T], 16);  accS[T]  += __shfl_xor(accS[T], 32);
    accV0[T] += __shfl_xor(accV0[T],16);  accV0[T] += __shfl_xor(accV0[T],32);
    accV1[T] += __shfl_xor(accV1[T],16);  accV1[T] += __shfl_xor(accV1[T],32);
    accV2[T] += __shfl_xor(accV2[T],16);  accV2[T] += __shfl_xor(accV2[T],32);
  }
  float oS  = (q&2) ? ((q&1)?accS[3] :accS[2])  : ((q&1)?accS[1] :accS[0]);
  float oV0 = (q&2) ? ((q&1)?accV0[3]:accV0[2]) : ((q&1)?accV0[1]:accV0[0]);
  float oV1 = (q&2) ? ((q&1)?accV1[3]:accV1[2]) : ((q&1)?accV1[1]:accV1[0]);
  float oV2 = (q&2) ? ((q&1)?accV2[3]:accV2[2]) : ((q&1)?accV2[1]:accV2[0]);
  ushort4 ov;
  ov.x = (unsigned short)f2bf(oS);
  ov.y = (unsigned short)f2bf(oV0);
  ov.z = (unsigned short)f2bf(oV1);
  ov.w = (unsigned short)f2bf(oV2);
  agg4[(size_t)n*64 + lane] = ov;
}

// ---- Node post-pass (R1 known-good structure) ----------------------------
__global__ __launch_bounds__(256) void k_node_post(
  const float* __restrict__ node_feats, const int* __restrict__ specie,
  const ushort4* __restrict__ agg4,
  const float* __restrict__ Wrst, const float* __restrict__ Wrvt,
  const float* __restrict__ W_out_s, const float* __restrict__ W_out_v,
  const float* __restrict__ W_prod_s, const float* __restrict__ W_prod_v,
  const float* __restrict__ W_lin_s, const float* __restrict__ W_lin_v,
  const float* __restrict__ W_read, float* __restrict__ out_node, float* __restrict__ out_feats)
{
  __shared__ float shA[4][4][64];
  __shared__ float shS[4][4][64];
  __shared__ float shP[4][4][64];
  int wave = threadIdx.x >> 6, lane = threadIdx.x & 63;
  int n = blockIdx.x*4 + wave;
  int o = n*64 + lane;
  ushort4 ag = agg4[(size_t)o];
  shA[wave][0][lane] = bfu2f(ag.x) * (1.f/16.f);
  shA[wave][1][lane] = bfu2f(ag.y) * (1.f/16.f);
  shA[wave][2][lane] = bfu2f(ag.z) * (1.f/16.f);
  shA[wave][3][lane] = bfu2f(ag.w) * (1.f/16.f);
  float4 nf = *(const float4*)(node_feats + (size_t)o*4);
  shS[wave][0][lane]=nf.x; shS[wave][1][lane]=nf.y; shS[wave][2][lane]=nf.z; shS[wave][3][lane]=nf.w;
  __syncthreads();
  int spec = specie[n];
  const float* Ws_ = Wrst + spec*4096;
  const float* Wv_ = Wrvt + spec*4096;
  float a_s=0.f,a0=0.f,a1=0.f,a2=0.f, r_s=0.f,r0=0.f,r1=0.f,r2=0.f;
  #pragma unroll 4
  for(int f=0; f<64; ++f){
    float wos=W_out_s[f*64+lane], wov=W_out_v[f*64+lane];
    a_s += shA[wave][0][f]*wos;
    a0  += shA[wave][1][f]*wov;
    a1  += shA[wave][2][f]*wov;
    a2  += shA[wave][3][f]*wov;
    float wrs=Ws_[f*64+lane], wrv=Wv_[f*64+lane];
    r_s += shS[wave][0][f]*wrs;
    r0  += shS[wave][1][f]*wrv;
    r1  += shS[wave][2][f]*wrv;
    r2  += shS[wave][3][f]*wrv;
  }
  a_s*=0.125f; a0*=0.125f; a1*=0.125f; a2*=0.125f;
  r_s*=0.125f; r0*=0.125f; r1*=0.125f; r2*=0.125f;
  float vv = a0*a0 + a1*a1 + a2*a2;
  float as2 = a_s*a_s;
  const float* Wp = W_prod_s + spec*320;
  float p_s = Wp[lane]*a_s + Wp[64+lane]*as2 + Wp[128+lane]*as2*a_s
            + Wp[192+lane]*vv + Wp[256+lane]*a_s*vv;
  const float* Wq = W_prod_v + spec*256;
  float coef = Wq[lane] + Wq[64+lane]*a_s + Wq[128+lane]*as2 + Wq[192+lane]*vv;
  shP[wave][0][lane] = p_s;
  shP[wave][1][lane] = coef*a0;
  shP[wave][2][lane] = coef*a1;
  shP[wave][3][lane] = coef*a2;
  __syncthreads();
  float fs=0.f,f0=0.f,f1=0.f,f2=0.f;
  #pragma unroll 4
  for(int f=0; f<64; ++f){
    float wls=W_lin_s[f*64+lane], wlv=W_lin_v[f*64+lane];
    fs += shP[wave][0][f]*wls;
    f0 += shP[wave][1][f]*wlv;
    f1 += shP[wave][2][f]*wlv;
    f2 += shP[wave][3][f]*wlv;
  }
  fs = fs*0.125f + r_s;
  f0 = f0*0.125f + r0;
  f1 = f1*0.125f + r1;
  f2 = f2*0.125f + r2;
  float x = fs * W_read[lane];
  #pragma unroll
  for(int off=32; off; off>>=1) x += __shfl_down(x, off);
  if(lane==0) out_node[n] = x*0.125f;
  float4 o4; o4.x=fs; o4.y=f0; o4.z=f1; o4.w=f2;
  *(float4*)(out_feats + (size_t)o*4) = o4;
}

extern "C" void kernel_launch(void* const* d_in, const int* in_sizes, int n_in,
                              void* d_out, int out_size, void* d_ws, size_t ws_size,
                              hipStream_t stream) {
  const float* vectors    = (const float*)d_in[0];
  const float* node_feats = (const float*)d_in[1];
  const int*   node_specie= (const int*)  d_in[2];
  const float* radial     = (const float*)d_in[3];
  const int*   senders    = (const int*)  d_in[4];
  const int*   receivers  = (const int*)  d_in[5];
  const float* W_res_s    = (const float*)d_in[6];
  const float* W_res_v    = (const float*)d_in[7];
  const float* W_in_s     = (const float*)d_in[8];
  const float* W_in_v     = (const float*)d_in[9];
  const float* mlp_w1     = (const float*)d_in[10];
  const float* mlp_w2     = (const float*)d_in[11];
  const float* W_out_s    = (const float*)d_in[12];
  const float* W_out_v    = (const float*)d_in[13];
  const float* W_prod_s   = (const float*)d_in[14];
  const float* W_prod_v   = (const float*)d_in[15];
  const float* W_lin_s    = (const float*)d_in[16];
  const float* W_lin_v    = (const float*)d_in[17];
  const float* W_read     = (const float*)d_in[18];

  float* ws = (float*)d_ws;
  ushort4* agg4 = (ushort4*)ws;                       // NF*8 B = 2*NF floats
  ushort4* h4   = (ushort4*)(ws + 2*(size_t)NF);      // 2*NF floats
  float* Wrst   = ws + 4*(size_t)NF;                  // 40960
  float* Wrvt   = Wrst + 40960;                       // 40960
  short* w2f    = (short*)(Wrvt + 40960);             // 20480 shorts = 10240 floats
  float* rperm  = Wrvt + 40960 + 10240;               // NE*8 + slack
  float4* vperm = (float4*)(rperm + (size_t)NE*8 + 128);  // NE + slack
  int* row_start= (int*)(rperm + (size_t)NE*8 + 128 + (size_t)NE*4 + 64);
  int* off2     = row_start + (NN+1);
  int* csr      = off2 + NN;

  hipMemsetAsync(off2, 0, (size_t)NN*sizeof(int), stream);
  k_hist<<<NE/256, 256, 0, stream>>>(receivers, off2);
  k_scan<<<1, 256, 0, stream>>>(off2, row_start, off2);
  k_scatter<<<NE/256, 256, 0, stream>>>(receivers, off2, csr);
  k_permute<<<NE/256, 256, 0, stream>>>(csr, radial, vectors, senders, rperm, vperm);
  k_prep_w2<<<80, 256, 0, stream>>>(mlp_w2, w2f);
  k_transpose_res<<<160, 256, 0, stream>>>(W_res_s, W_res_v, Wrst, Wrvt);
  k_node_pre<<<NN/4, 256, 0, stream>>>(node_feats, W_in_s, W_in_v, h4);
  k_edge_recv<<<NN/4, 256, 0, stream>>>(row_start, rperm, vperm, mlp_w1, w2f, h4, agg4);
  k_node_post<<<NN/4, 256, 0, stream>>>(node_feats, node_specie, agg4,
                                        Wrst, Wrvt, W_out_s, W_out_v,
                                        W_prod_s, W_prod_v, W_lin_s, W_lin_v,
                                        W_read, (float*)d_out, (float*)d_out + NN);
}